// Round 7
// baseline (2346.489 us; speedup 1.0000x reference)
//
#include <hip/hip_runtime.h>

#define N_POINTS    100000
#define N_KEYPOINTS 16384
#define N_PAIRS     524288
#define D_OUT       300
#define TP          64     // pairs per LDS tile
#define PB          32     // phase-2 pair block (acc regs = 2*PB)
#define TR          32     // output-MLP row tile

// ---------------------------------------------------------------------------
// CSR build: count pairs per keypoint, exclusive scan, fill sorted pair list.
// ---------------------------------------------------------------------------
__global__ __launch_bounds__(256) void k_count(const int* __restrict__ si_set,
                                               int* __restrict__ cnt) {
    const int s = blockIdx.x * 256 + threadIdx.x;
    if (s < N_PAIRS) atomicAdd(&cnt[si_set[s]], 1);
}

__global__ __launch_bounds__(256) void k_scan(const int* __restrict__ cnt,
                                              int* __restrict__ off,
                                              int* __restrict__ cursor) {
    __shared__ int part[256];
    const int t = threadIdx.x;
    const int base = t * 64;   // 16384 / 256
    int s = 0;
    for (int k = 0; k < 64; ++k) s += cnt[base + k];
    part[t] = s;
    __syncthreads();
    for (int d = 1; d < 256; d <<= 1) {
        int add = (t >= d) ? part[t - d] : 0;
        __syncthreads();
        part[t] += add;
        __syncthreads();
    }
    int run = part[t] - s;
    for (int k = 0; k < 64; ++k) {
        off[base + k] = run;
        cursor[base + k] = run;
        run += cnt[base + k];
    }
    if (t == 255) off[N_KEYPOINTS] = run;
}

__global__ __launch_bounds__(256) void k_fill(const int* __restrict__ si_set,
                                              int* __restrict__ cursor,
                                              int* __restrict__ pairlist) {
    const int s = blockIdx.x * 256 + threadIdx.x;
    if (s < N_PAIRS) {
        const int st = si_set[s];
        const int pos = atomicAdd(&cursor[st], 1);
        pairlist[pos] = s;
    }
}

// ---------------------------------------------------------------------------
// Fused point MLP + segmented max. Block = 2 keypoints, 320 threads.
// Round-6 post-mortem: stuck at 1.93ms with VALUBusy 33% -- weight fetch was
// serialized (s_load chains inside 1c's k-loop; 2 VMEM per k in phase 2 with
// ~200cy L2 latency exposed). This version:
//   - pw3 staged in LDS once per block -> 1c weights are broadcast
//     ds_read_b128 (uniform addr, conflict-free), no scalar-load chains.
//   - 1c k-outer: acc[32] persists, per k: 1 b32 x2 read + 8 b128 w3 + 32 FMA
//   - phase 2 k-outer, PB=32: acc0[32]+acc1[32] persist; per k: 2 coalesced
//     VMEM (pipelined, unroll 2) + 8 broadcast b128 + 64 FMA.
// LDS = 32K(w3L) + 16K(x2T) + 32K(x3T) = 80 KB -> 2 blocks/CU.
// ---------------------------------------------------------------------------
__global__ __launch_bounds__(320, 2) void fused_point(
    const float* __restrict__ features, const float* __restrict__ coords,
    const int* __restrict__ keypoints, const int* __restrict__ set_indices,
    const int* __restrict__ pairlist, const int* __restrict__ off,
    const float* __restrict__ pw1, const float* __restrict__ pb1,
    const float* __restrict__ pw2, const float* __restrict__ pb2,
    const float* __restrict__ pw3, const float* __restrict__ pb3,
    const float* __restrict__ pw4, const float* __restrict__ pb4,
    float* __restrict__ agg)
{
    __shared__ float w3L[64 * 128];   // 32 KB  staged pw3
    __shared__ float x2T[64][TP];     // 16 KB  [col][pair]
    __shared__ float x3T[128][TP];    // 32 KB  [col][pair]

    const int t  = threadIdx.x;
    const int gA = blockIdx.x * 2;
    const int p  = t & 63;                                  // pair lane
    const int qq = __builtin_amdgcn_readfirstlane(t >> 6);  // wave id 0..4

    // ---- one-time: stage pw3 into LDS (coalesced) ----
    for (int i = t; i < 64 * 128; i += 320) w3L[i] = pw3[i];

    const int base   = off[gA];
    const int endAll = off[gA + 2];
    const int nt     = (endAll - base + TP - 1) >> 6;

    const bool p2act = (t < 300);
    const int  cc    = (t < 150) ? t : t - 150;   // column base (cc, cc+150)
    const int  gsel  = (t < 150) ? 0 : 1;
    const int  gs    = off[gA + gsel];
    const int  ge    = off[gA + gsel + 1];
    float vmax0 = -INFINITY, vmax1 = -INFINITY;

    __syncthreads();   // w3L ready

    for (int it = 0; it < nt; ++it) {
        const int t0 = base + (it << 6);
        int np = endAll - t0; if (np > TP) np = TP;

        // ---- 1b: gather + layer 1 (regs) + layer 2 quarter -> x2T ----
        if (qq < 4 && p < np) {
            const int pair = pairlist[t0 + p];
            const int pt = set_indices[pair];
            const int st = set_indices[N_PAIRS + pair];
            const int kp = keypoints[st];

            float x0[4];
            x0[0] = features[pt];
            x0[1] = coords[pt * 3 + 0] - coords[kp * 3 + 0];
            x0[2] = coords[pt * 3 + 1] - coords[kp * 3 + 1];
            x0[3] = coords[pt * 3 + 2] - coords[kp * 3 + 2];

            float x1[32];
#pragma unroll
            for (int j = 0; j < 32; ++j) {
                float a = pb1[j];
#pragma unroll
                for (int k = 0; k < 4; ++k) a = fmaf(x0[k], pw1[k * 32 + j], a);
                x1[j] = fmaxf(a, 0.f);
            }

            const int jc = qq << 4;            // 0,16,32,48 (wave-uniform)
            float acc[16];
#pragma unroll
            for (int jj = 0; jj < 16; ++jj) acc[jj] = pb2[jc + jj];
#pragma unroll
            for (int k = 0; k < 32; ++k) {     // full unroll: x1[k] static
                const float xk = x1[k];
#pragma unroll
                for (int jj = 0; jj < 16; ++jj)
                    acc[jj] = fmaf(xk, pw2[k * 64 + jc + jj], acc[jj]);
            }
#pragma unroll
            for (int jj = 0; jj < 16; ++jj)
                x2T[jc + jj][p] = fmaxf(acc[jj], 0.f);
        }
        __syncthreads();

        // ---- 1c: layer 3 (64 -> 128), k-outer, w3 from LDS broadcasts ----
        if (qq < 4 && p < np) {
            const int jc = qq << 5;            // 0,32,64,96 (wave-uniform)
            float acc[32];
#pragma unroll
            for (int jj = 0; jj < 32; ++jj) acc[jj] = pb3[jc + jj];
            for (int k = 0; k < 64; ++k) {
                const float xk = x2T[k][p];
#pragma unroll
                for (int u = 0; u < 8; ++u) {
                    const float4 wv = *(const float4*)&w3L[k * 128 + jc + 4 * u];
                    acc[4*u+0] = fmaf(xk, wv.x, acc[4*u+0]);
                    acc[4*u+1] = fmaf(xk, wv.y, acc[4*u+1]);
                    acc[4*u+2] = fmaf(xk, wv.z, acc[4*u+2]);
                    acc[4*u+3] = fmaf(xk, wv.w, acc[4*u+3]);
                }
            }
#pragma unroll
            for (int jj = 0; jj < 32; ++jj)
                x3T[jc + jj][p] = fmaxf(acc[jj], 0.f);
        }
        __syncthreads();

        // ---- 2: layer 4 (128 -> 300) + running segmented max ----
        if (p2act) {
            int as = gs - t0; if (as < 0) as = 0;
            int ae = ge - t0; if (ae > np) ae = np;
            for (int jb = (as & ~(PB - 1)); jb < ae; jb += PB) {
                float acc0[PB], acc1[PB];
#pragma unroll
                for (int i = 0; i < PB; ++i) { acc0[i] = 0.f; acc1[i] = 0.f; }
#pragma unroll 2
                for (int k = 0; k < 128; ++k) {
                    const float wa = pw4[k * D_OUT + cc];
                    const float wb = pw4[k * D_OUT + cc + 150];
#pragma unroll
                    for (int u = 0; u < PB / 4; ++u) {
                        const float4 xv = *(const float4*)&x3T[k][jb + 4 * u];
                        acc0[4*u+0] = fmaf(xv.x, wa, acc0[4*u+0]);
                        acc0[4*u+1] = fmaf(xv.y, wa, acc0[4*u+1]);
                        acc0[4*u+2] = fmaf(xv.z, wa, acc0[4*u+2]);
                        acc0[4*u+3] = fmaf(xv.w, wa, acc0[4*u+3]);
                        acc1[4*u+0] = fmaf(xv.x, wb, acc1[4*u+0]);
                        acc1[4*u+1] = fmaf(xv.y, wb, acc1[4*u+1]);
                        acc1[4*u+2] = fmaf(xv.z, wb, acc1[4*u+2]);
                        acc1[4*u+3] = fmaf(xv.w, wb, acc1[4*u+3]);
                    }
                }
#pragma unroll
                for (int i = 0; i < PB; ++i) {
                    const int s = jb + i;
                    if (s >= as && s < ae) {
                        vmax0 = fmaxf(vmax0, acc0[i]);
                        vmax1 = fmaxf(vmax1, acc1[i]);
                    }
                }
            }
        }
        __syncthreads();
    }

    if (p2act) {
        const int g = gA + gsel;
        // empty segment: vmax=-inf -> relu gives 0 (matches max(segmax,0))
        agg[(size_t)g * D_OUT + cc]       = fmaxf(vmax0 + pb4[cc], 0.f);
        agg[(size_t)g * D_OUT + cc + 150] = fmaxf(vmax1 + pb4[cc + 150], 0.f);
    }
}

// ---------------------------------------------------------------------------
// Output MLP (unchanged; in-place safe: block reads its 32 rows before write).
// ---------------------------------------------------------------------------
__global__ __launch_bounds__(320, 2) void out_mlp(
    const float* __restrict__ agg,
    const float* __restrict__ ow1, const float* __restrict__ ob1,
    const float* __restrict__ ow2, const float* __restrict__ ob2,
    float* __restrict__ y)
{
    __shared__ float A[TR * D_OUT];
    __shared__ float H[TR * D_OUT];
    const int t = threadIdx.x;
    const long rb = (long)blockIdx.x * TR;

    for (int l = t; l < TR * D_OUT; l += 320) A[l] = agg[rb * D_OUT + l];
    __syncthreads();

    if (t < D_OUT) {
        float acc[TR];
#pragma unroll
        for (int r = 0; r < TR; ++r) acc[r] = ob1[t];
        for (int k = 0; k < D_OUT; k += 4) {
            const float w0 = ow1[(k + 0) * D_OUT + t];
            const float w1 = ow1[(k + 1) * D_OUT + t];
            const float w2 = ow1[(k + 2) * D_OUT + t];
            const float w3 = ow1[(k + 3) * D_OUT + t];
#pragma unroll
            for (int r = 0; r < TR; ++r) {
                const float4 a4 = *reinterpret_cast<const float4*>(&A[r * D_OUT + k]);
                acc[r] = fmaf(a4.x, w0, acc[r]);
                acc[r] = fmaf(a4.y, w1, acc[r]);
                acc[r] = fmaf(a4.z, w2, acc[r]);
                acc[r] = fmaf(a4.w, w3, acc[r]);
            }
        }
#pragma unroll
        for (int r = 0; r < TR; ++r) H[r * D_OUT + t] = fmaxf(acc[r], 0.f);
    }
    __syncthreads();

    if (t < D_OUT) {
        float acc[TR];
#pragma unroll
        for (int r = 0; r < TR; ++r) acc[r] = ob2[t];
        for (int k = 0; k < D_OUT; k += 4) {
            const float w0 = ow2[(k + 0) * D_OUT + t];
            const float w1 = ow2[(k + 1) * D_OUT + t];
            const float w2 = ow2[(k + 2) * D_OUT + t];
            const float w3 = ow2[(k + 3) * D_OUT + t];
#pragma unroll
            for (int r = 0; r < TR; ++r) {
                const float4 h4 = *reinterpret_cast<const float4*>(&H[r * D_OUT + k]);
                acc[r] = fmaf(h4.x, w0, acc[r]);
                acc[r] = fmaf(h4.y, w1, acc[r]);
                acc[r] = fmaf(h4.z, w2, acc[r]);
                acc[r] = fmaf(h4.w, w3, acc[r]);
            }
        }
#pragma unroll
        for (int r = 0; r < TR; ++r) y[(rb + r) * D_OUT + t] = fmaxf(acc[r], 0.f);
    }
}

extern "C" void kernel_launch(void* const* d_in, const int* in_sizes, int n_in,
                              void* d_out, int out_size, void* d_ws, size_t ws_size,
                              hipStream_t stream) {
    const float* features    = (const float*)d_in[0];
    const float* coords      = (const float*)d_in[1];
    const int*   keypoints   = (const int*)d_in[2];
    const int*   set_indices = (const int*)d_in[3];
    const float* pw1 = (const float*)d_in[4];
    const float* pb1 = (const float*)d_in[5];
    const float* pw2 = (const float*)d_in[6];
    const float* pb2 = (const float*)d_in[7];
    const float* pw3 = (const float*)d_in[8];
    const float* pb3 = (const float*)d_in[9];
    const float* pw4 = (const float*)d_in[10];
    const float* pb4 = (const float*)d_in[11];
    const float* ow1 = (const float*)d_in[12];
    const float* ob1 = (const float*)d_in[13];
    const float* ow2 = (const float*)d_in[14];
    const float* ob2 = (const float*)d_in[15];

    const int* si_set = set_indices + N_PAIRS;

    // ws layout: CSR only (~2.2 MB)
    char* w = (char*)d_ws;
    int* cnt      = (int*)w;  w += 65536;
    int* off      = (int*)w;  w += 65792;   // 16385 ints, padded
    int* cursor   = (int*)w;  w += 65536;
    int* pairlist = (int*)w;

    float* agg = (float*)d_out;   // out_mlp runs in-place (read-before-write)
    float* y   = (float*)d_out;

    hipMemsetAsync(cnt, 0, 65536, stream);
    k_count<<<N_PAIRS / 256, 256, 0, stream>>>(si_set, cnt);
    k_scan<<<1, 256, 0, stream>>>(cnt, off, cursor);
    k_fill<<<N_PAIRS / 256, 256, 0, stream>>>(si_set, cursor, pairlist);

    fused_point<<<N_KEYPOINTS / 2, 320, 0, stream>>>(
        features, coords, keypoints, set_indices, pairlist, off,
        pw1, pb1, pw2, pb2, pw3, pb3, pw4, pb4, agg);

    out_mlp<<<N_KEYPOINTS / TR, 320, 0, stream>>>(agg, ow1, ob1, ow2, ob2, y);
}

// Round 8
// 1408.292 us; speedup vs baseline: 1.6662x; 1.6662x over previous
//
#include <hip/hip_runtime.h>

#define N_POINTS    100000
#define N_KEYPOINTS 16384
#define N_PAIRS     524288
#define D_OUT       300
#define NTILES      19     // ceil(304/16) column tiles for layer 4
#define TP          64     // pairs per LDS tile
#define TR          32     // output-MLP row tile

typedef __attribute__((ext_vector_type(8))) short short8;   // 8 bf16 (4 VGPRs)
typedef __attribute__((ext_vector_type(4))) float f32x4;

__device__ inline unsigned short f2bf(float f) {           // RNE fp32 -> bf16
    unsigned u = __builtin_bit_cast(unsigned, f);
    u += 0x7FFFu + ((u >> 16) & 1u);
    return (unsigned short)(u >> 16);
}
__device__ inline float bf2f(unsigned short h) {
    unsigned u = ((unsigned)h) << 16;
    return __builtin_bit_cast(float, u);
}

// ---------------------------------------------------------------------------
// CSR build: count pairs per keypoint, exclusive scan, fill sorted pair list.
// ---------------------------------------------------------------------------
__global__ __launch_bounds__(256) void k_count(const int* __restrict__ si_set,
                                               int* __restrict__ cnt) {
    const int s = blockIdx.x * 256 + threadIdx.x;
    if (s < N_PAIRS) atomicAdd(&cnt[si_set[s]], 1);
}

__global__ __launch_bounds__(256) void k_scan(const int* __restrict__ cnt,
                                              int* __restrict__ off,
                                              int* __restrict__ cursor) {
    __shared__ int part[256];
    const int t = threadIdx.x;
    const int base = t * 64;   // 16384 / 256
    int s = 0;
    for (int k = 0; k < 64; ++k) s += cnt[base + k];
    part[t] = s;
    __syncthreads();
    for (int d = 1; d < 256; d <<= 1) {
        int add = (t >= d) ? part[t - d] : 0;
        __syncthreads();
        part[t] += add;
        __syncthreads();
    }
    int run = part[t] - s;
    for (int k = 0; k < 64; ++k) {
        off[base + k] = run;
        cursor[base + k] = run;
        run += cnt[base + k];
    }
    if (t == 255) off[N_KEYPOINTS] = run;
}

__global__ __launch_bounds__(256) void k_fill(const int* __restrict__ si_set,
                                              int* __restrict__ cursor,
                                              int* __restrict__ pairlist) {
    const int s = blockIdx.x * 256 + threadIdx.x;
    if (s < N_PAIRS) {
        const int st = si_set[s];
        const int pos = atomicAdd(&cursor[st], 1);
        pairlist[pos] = s;
    }
}

// ---------------------------------------------------------------------------
// Prep: pack W4 (128x300 fp32) into MFMA B-fragment order, split bf16 hi/lo.
// Fragment (s,n): lane l holds cols 16n+(l&15), k = 32s+(l>>4)*8+i, i=0..7.
// Linear index ((s*NTILES+n)*64+lane)*8+i  -> lane-contiguous 16B loads.
// ---------------------------------------------------------------------------
__global__ __launch_bounds__(256) void k_w4frag(const float* __restrict__ pw4,
                                                unsigned short* __restrict__ w4fh,
                                                unsigned short* __restrict__ w4fl) {
    const int tid = blockIdx.x * 256 + threadIdx.x;
    if (tid >= 4 * NTILES * 64) return;
    const int lane = tid & 63;
    const int sn = tid >> 6;
    const int s = sn / NTILES, n = sn % NTILES;
#pragma unroll
    for (int i = 0; i < 8; ++i) {
        const int k = 32 * s + ((lane >> 4) << 3) + i;
        const int col = 16 * n + (lane & 15);
        const float v = (col < D_OUT) ? pw4[k * D_OUT + col] : 0.f;
        const unsigned short h = f2bf(v);
        w4fh[(size_t)tid * 8 + i] = h;
        w4fl[(size_t)tid * 8 + i] = f2bf(v - bf2f(h));
    }
}

// ---------------------------------------------------------------------------
// Fused point MLP + segmented max. Block = 2 keypoints, 320 threads (5 waves).
//   1b (waves 0-3, lane=pair): gather + layer1 (regs) + layer2 quarter -> x2T
//   1c (waves 0-3): layer 3 quarter fp32, write x3 as split-bf16 A-FRAGMENTS
//       into LDS (frag order -> conflict-free b128); zero-fill tail slots.
//   ph2 (all 5 waves): layer 4 via mfma_f32_16x16x32_bf16, 3-term split
//       (hh+lh+hl, fp32 acc ~ full precision). Wave w covers col tiles
//       w,w+5,w+10,w+15. Per-lane running segmented max over its 16 rows,
//       then shfl_xor(16/32) column reduce, direct agg store. No atomics.
// 2 barriers/tile: ph2 overlaps the next tile's 1b.
// LDS = 16K (x2T) + 16K (a3h) + 16K (a3l) = 48 KB.
// ---------------------------------------------------------------------------
__global__ __launch_bounds__(320, 2) void fused_point(
    const float* __restrict__ features, const float* __restrict__ coords,
    const int* __restrict__ keypoints, const int* __restrict__ set_indices,
    const int* __restrict__ pairlist, const int* __restrict__ off,
    const float* __restrict__ pw1, const float* __restrict__ pb1,
    const float* __restrict__ pw2, const float* __restrict__ pb2,
    const float* __restrict__ pw3, const float* __restrict__ pb3,
    const short8* __restrict__ w4fh, const short8* __restrict__ w4fl,
    const float* __restrict__ pb4,
    float* __restrict__ agg)
{
    __shared__ float  x2T[64][TP];   // 16 KB [feature][pair]
    __shared__ short8 a3h[1024];     // 16 KB x3 hi frags: (s*4+m)*64+lane
    __shared__ short8 a3l[1024];     // 16 KB x3 lo frags

    const int t    = threadIdx.x;
    const int gA   = blockIdx.x * 2;
    const int lane = t & 63;                                 // pair slot / mfma lane
    const int qq   = __builtin_amdgcn_readfirstlane(t >> 6); // wave id 0..4

    const int base   = off[gA];
    const int bnd    = off[gA + 1];
    const int endAll = off[gA + 2];
    const int nt     = (endAll - base + TP - 1) >> 6;

    float vA[4] = {-INFINITY, -INFINITY, -INFINITY, -INFINITY};
    float vB[4] = {-INFINITY, -INFINITY, -INFINITY, -INFINITY};

    for (int it = 0; it < nt; ++it) {
        const int t0 = base + (it << 6);
        int np = endAll - t0; if (np > TP) np = TP;

        // ---- 1b: gather + layer 1 (regs) + layer 2 quarter -> x2T ----
        if (qq < 4 && lane < np) {
            const int pair = pairlist[t0 + lane];
            const int pt = set_indices[pair];
            const int st = set_indices[N_PAIRS + pair];
            const int kp = keypoints[st];

            float x0[4];
            x0[0] = features[pt];
            x0[1] = coords[pt * 3 + 0] - coords[kp * 3 + 0];
            x0[2] = coords[pt * 3 + 1] - coords[kp * 3 + 1];
            x0[3] = coords[pt * 3 + 2] - coords[kp * 3 + 2];

            float x1[32];
#pragma unroll
            for (int j = 0; j < 32; ++j) {
                float a = pb1[j];
#pragma unroll
                for (int k = 0; k < 4; ++k) a = fmaf(x0[k], pw1[k * 32 + j], a);
                x1[j] = fmaxf(a, 0.f);
            }

            const int jc = qq << 4;            // 0,16,32,48 (wave-uniform)
            float acc[16];
#pragma unroll
            for (int jj = 0; jj < 16; ++jj) acc[jj] = pb2[jc + jj];
#pragma unroll
            for (int k = 0; k < 32; ++k) {
                const float xk = x1[k];
#pragma unroll
                for (int jj = 0; jj < 16; ++jj)
                    acc[jj] = fmaf(xk, pw2[k * 64 + jc + jj], acc[jj]);
            }
#pragma unroll
            for (int jj = 0; jj < 16; ++jj)
                x2T[jc + jj][lane] = fmaxf(acc[jj], 0.f);
        }
        __syncthreads();

        // ---- 1c: layer 3 quarter fp32 -> split-bf16 A-fragments in LDS ----
        if (qq < 4) {
            const int jc2 = qq << 5;           // 0,32,64,96 (wave-uniform)
            const bool ok = (lane < np);
            float acc3[32];
#pragma unroll
            for (int jj = 0; jj < 32; ++jj) acc3[jj] = pb3[jc2 + jj];
            if (ok) {
                for (int k = 0; k < 64; ++k) {
                    const float xk = x2T[k][lane];
#pragma unroll
                    for (int jj = 0; jj < 32; ++jj)
                        acc3[jj] = fmaf(xk, pw3[k * 128 + jc2 + jj], acc3[jj]);
                }
            }
            // x3 feature f = jc2+jj maps to frag s=qq, i=jj&7, group g=jj>>3:
            // lane' = (pair&15)+16g, m = pair>>4. 16B-contiguous per group.
#pragma unroll
            for (int g = 0; g < 4; ++g) {
                short8 vh, vl;
#pragma unroll
                for (int i = 0; i < 8; ++i) {
                    const float v = ok ? fmaxf(acc3[g * 8 + i], 0.f) : 0.f;
                    const unsigned short h = f2bf(v);
                    vh[i] = (short)h;
                    vl[i] = (short)f2bf(v - bf2f(h));
                }
                const int fi = (qq * 4 + (lane >> 4)) * 64 + (lane & 15) + 16 * g;
                a3h[fi] = vh;
                a3l[fi] = vl;
            }
        }
        __syncthreads();

        // ---- ph2: layer 4 MFMA (split-bf16, 3 terms) + running seg-max ----
        {
            f32x4 acc[4][4];
#pragma unroll
            for (int m = 0; m < 4; ++m)
#pragma unroll
                for (int j = 0; j < 4; ++j)
                    acc[m][j] = (f32x4){0.f, 0.f, 0.f, 0.f};

#pragma unroll
            for (int s = 0; s < 4; ++s) {
                short8 ah[4], al[4];
#pragma unroll
                for (int m = 0; m < 4; ++m) {
                    ah[m] = a3h[(s * 4 + m) * 64 + lane];
                    al[m] = a3l[(s * 4 + m) * 64 + lane];
                }
#pragma unroll
                for (int j = 0; j < 4; ++j) {
                    const int gn = qq + 5 * j;          // wave-uniform
                    if (gn < NTILES) {
                        const short8 bh = w4fh[(s * NTILES + gn) * 64 + lane];
                        const short8 bl = w4fl[(s * NTILES + gn) * 64 + lane];
#pragma unroll
                        for (int m = 0; m < 4; ++m) {
                            acc[m][j] = __builtin_amdgcn_mfma_f32_16x16x32_bf16(ah[m], bh, acc[m][j], 0, 0, 0);
                            acc[m][j] = __builtin_amdgcn_mfma_f32_16x16x32_bf16(al[m], bh, acc[m][j], 0, 0, 0);
                            acc[m][j] = __builtin_amdgcn_mfma_f32_16x16x32_bf16(ah[m], bl, acc[m][j], 0, 0, 0);
                        }
                    }
                }
            }

            // C/D: col = lane&15 (within tile), row = (lane>>4)*4 + reg + 16m
            const int rb0 = (lane >> 4) << 2;
#pragma unroll
            for (int m = 0; m < 4; ++m) {
#pragma unroll
                for (int r = 0; r < 4; ++r) {
                    const int g = t0 + 16 * m + rb0 + r;
                    const bool vld = (g < endAll);
                    const bool inA = (g < bnd);
#pragma unroll
                    for (int j = 0; j < 4; ++j) {
                        const float c = acc[m][j][r];
                        vA[j] = (vld && inA)  ? fmaxf(vA[j], c) : vA[j];
                        vB[j] = (vld && !inA) ? fmaxf(vB[j], c) : vB[j];
                    }
                }
            }
        }
        __syncthreads();   // protect a3h/a3l before next tile's 1c
    }

    // column-wise reduce across the 4 row-groups; lanes 0-15 hold all cols
#pragma unroll
    for (int j = 0; j < 4; ++j) {
        vA[j] = fmaxf(vA[j], __shfl_xor(vA[j], 16));
        vA[j] = fmaxf(vA[j], __shfl_xor(vA[j], 32));
        vB[j] = fmaxf(vB[j], __shfl_xor(vB[j], 16));
        vB[j] = fmaxf(vB[j], __shfl_xor(vB[j], 32));
    }
    if (lane < 16) {
#pragma unroll
        for (int j = 0; j < 4; ++j) {
            const int gn = qq + 5 * j;
            const int col = 16 * gn + lane;
            if (gn < NTILES && col < D_OUT) {
                // empty segment: -inf + bias -> relu gives 0 (= max(segmax,0))
                agg[(size_t)gA * D_OUT + col]       = fmaxf(vA[j] + pb4[col], 0.f);
                agg[(size_t)(gA + 1) * D_OUT + col] = fmaxf(vB[j] + pb4[col], 0.f);
            }
        }
    }
}

// ---------------------------------------------------------------------------
// Output MLP (unchanged; in-place safe: block reads its 32 rows before write).
// ---------------------------------------------------------------------------
__global__ __launch_bounds__(320, 2) void out_mlp(
    const float* __restrict__ agg,
    const float* __restrict__ ow1, const float* __restrict__ ob1,
    const float* __restrict__ ow2, const float* __restrict__ ob2,
    float* __restrict__ y)
{
    __shared__ float A[TR * D_OUT];
    __shared__ float H[TR * D_OUT];
    const int t = threadIdx.x;
    const long rb = (long)blockIdx.x * TR;

    for (int l = t; l < TR * D_OUT; l += 320) A[l] = agg[rb * D_OUT + l];
    __syncthreads();

    if (t < D_OUT) {
        float acc[TR];
#pragma unroll
        for (int r = 0; r < TR; ++r) acc[r] = ob1[t];
        for (int k = 0; k < D_OUT; k += 4) {
            const float w0 = ow1[(k + 0) * D_OUT + t];
            const float w1 = ow1[(k + 1) * D_OUT + t];
            const float w2 = ow1[(k + 2) * D_OUT + t];
            const float w3 = ow1[(k + 3) * D_OUT + t];
#pragma unroll
            for (int r = 0; r < TR; ++r) {
                const float4 a4 = *reinterpret_cast<const float4*>(&A[r * D_OUT + k]);
                acc[r] = fmaf(a4.x, w0, acc[r]);
                acc[r] = fmaf(a4.y, w1, acc[r]);
                acc[r] = fmaf(a4.z, w2, acc[r]);
                acc[r] = fmaf(a4.w, w3, acc[r]);
            }
        }
#pragma unroll
        for (int r = 0; r < TR; ++r) H[r * D_OUT + t] = fmaxf(acc[r], 0.f);
    }
    __syncthreads();

    if (t < D_OUT) {
        float acc[TR];
#pragma unroll
        for (int r = 0; r < TR; ++r) acc[r] = ob2[t];
        for (int k = 0; k < D_OUT; k += 4) {
            const float w0 = ow2[(k + 0) * D_OUT + t];
            const float w1 = ow2[(k + 1) * D_OUT + t];
            const float w2 = ow2[(k + 2) * D_OUT + t];
            const float w3 = ow2[(k + 3) * D_OUT + t];
#pragma unroll
            for (int r = 0; r < TR; ++r) {
                const float4 h4 = *reinterpret_cast<const float4*>(&H[r * D_OUT + k]);
                acc[r] = fmaf(h4.x, w0, acc[r]);
                acc[r] = fmaf(h4.y, w1, acc[r]);
                acc[r] = fmaf(h4.z, w2, acc[r]);
                acc[r] = fmaf(h4.w, w3, acc[r]);
            }
        }
#pragma unroll
        for (int r = 0; r < TR; ++r) y[(rb + r) * D_OUT + t] = fmaxf(acc[r], 0.f);
    }
}

extern "C" void kernel_launch(void* const* d_in, const int* in_sizes, int n_in,
                              void* d_out, int out_size, void* d_ws, size_t ws_size,
                              hipStream_t stream) {
    const float* features    = (const float*)d_in[0];
    const float* coords      = (const float*)d_in[1];
    const int*   keypoints   = (const int*)d_in[2];
    const int*   set_indices = (const int*)d_in[3];
    const float* pw1 = (const float*)d_in[4];
    const float* pb1 = (const float*)d_in[5];
    const float* pw2 = (const float*)d_in[6];
    const float* pb2 = (const float*)d_in[7];
    const float* pw3 = (const float*)d_in[8];
    const float* pb3 = (const float*)d_in[9];
    const float* pw4 = (const float*)d_in[10];
    const float* pb4 = (const float*)d_in[11];
    const float* ow1 = (const float*)d_in[12];
    const float* ob1 = (const float*)d_in[13];
    const float* ow2 = (const float*)d_in[14];
    const float* ob2 = (const float*)d_in[15];

    const int* si_set = set_indices + N_PAIRS;

    // ws layout (~2.6 MB): cnt | off | cursor | w4fh | w4fl | pairlist
    char* w = (char*)d_ws;
    int*            cnt      = (int*)w;             w += 65536;
    int*            off      = (int*)w;             w += 65792;
    int*            cursor   = (int*)w;             w += 65536;
    unsigned short* w4fh     = (unsigned short*)w;  w += 4 * NTILES * 64 * 8 * 2;  // 77824
    unsigned short* w4fl     = (unsigned short*)w;  w += 4 * NTILES * 64 * 8 * 2;  // 77824
    int*            pairlist = (int*)w;

    float* agg = (float*)d_out;   // out_mlp runs in-place (read-before-write)
    float* y   = (float*)d_out;

    hipMemsetAsync(cnt, 0, 65536, stream);
    k_w4frag<<<(4 * NTILES * 64 + 255) / 256, 256, 0, stream>>>(pw4, w4fh, w4fl);
    k_count<<<N_PAIRS / 256, 256, 0, stream>>>(si_set, cnt);
    k_scan<<<1, 256, 0, stream>>>(cnt, off, cursor);
    k_fill<<<N_PAIRS / 256, 256, 0, stream>>>(si_set, cursor, pairlist);

    fused_point<<<N_KEYPOINTS / 2, 320, 0, stream>>>(
        features, coords, keypoints, set_indices, pairlist, off,
        pw1, pb1, pw2, pb2, pw3, pb3,
        (const short8*)w4fh, (const short8*)w4fl, pb4, agg);

    out_mlp<<<N_KEYPOINTS / TR, 320, 0, stream>>>(agg, ow1, ob1, ow2, ob2, y);
}

// Round 9
// 875.505 us; speedup vs baseline: 2.6802x; 1.6085x over previous
//
#include <hip/hip_runtime.h>

#define N_POINTS    100000
#define N_KEYPOINTS 16384
#define N_PAIRS     524288
#define D_OUT       300
#define NTILES      19     // ceil(304/16) column tiles for layer 4
#define TP          64     // pairs per LDS tile
#define TR          16     // output-MLP row tile

typedef __attribute__((ext_vector_type(8))) short short8;   // 8 bf16 (4 VGPRs)
typedef __attribute__((ext_vector_type(4))) float f32x4;

__device__ inline unsigned short f2bf(float f) {           // RNE fp32 -> bf16
    unsigned u = __builtin_bit_cast(unsigned, f);
    u += 0x7FFFu + ((u >> 16) & 1u);
    return (unsigned short)(u >> 16);
}
__device__ inline float bf2f(unsigned short h) {
    unsigned u = ((unsigned)h) << 16;
    return __builtin_bit_cast(float, u);
}

// ---------------------------------------------------------------------------
// CSR build: count pairs per keypoint, exclusive scan, fill sorted pair list.
// ---------------------------------------------------------------------------
__global__ __launch_bounds__(256) void k_count(const int* __restrict__ si_set,
                                               int* __restrict__ cnt) {
    const int s = blockIdx.x * 256 + threadIdx.x;
    if (s < N_PAIRS) atomicAdd(&cnt[si_set[s]], 1);
}

__global__ __launch_bounds__(256) void k_scan(const int* __restrict__ cnt,
                                              int* __restrict__ off,
                                              int* __restrict__ cursor) {
    __shared__ int part[256];
    const int t = threadIdx.x;
    const int base = t * 64;   // 16384 / 256
    int s = 0;
    for (int k = 0; k < 64; ++k) s += cnt[base + k];
    part[t] = s;
    __syncthreads();
    for (int d = 1; d < 256; d <<= 1) {
        int add = (t >= d) ? part[t - d] : 0;
        __syncthreads();
        part[t] += add;
        __syncthreads();
    }
    int run = part[t] - s;
    for (int k = 0; k < 64; ++k) {
        off[base + k] = run;
        cursor[base + k] = run;
        run += cnt[base + k];
    }
    if (t == 255) off[N_KEYPOINTS] = run;
}

__global__ __launch_bounds__(256) void k_fill(const int* __restrict__ si_set,
                                              int* __restrict__ cursor,
                                              int* __restrict__ pairlist) {
    const int s = blockIdx.x * 256 + threadIdx.x;
    if (s < N_PAIRS) {
        const int st = si_set[s];
        const int pos = atomicAdd(&cursor[st], 1);
        pairlist[pos] = s;
    }
}

// ---------------------------------------------------------------------------
// Prep: pack W4 (128x300) into MFMA B-fragment order, split bf16 hi/lo.
// Fragment (s,n): lane l holds cols 16n+(l&15), k = 32s+(l>>4)*8+i.
// ---------------------------------------------------------------------------
__global__ __launch_bounds__(256) void k_w4frag(const float* __restrict__ pw4,
                                                unsigned short* __restrict__ w4fh,
                                                unsigned short* __restrict__ w4fl) {
    const int tid = blockIdx.x * 256 + threadIdx.x;
    if (tid >= 4 * NTILES * 64) return;
    const int lane = tid & 63;
    const int sn = tid >> 6;
    const int s = sn / NTILES, n = sn % NTILES;
#pragma unroll
    for (int i = 0; i < 8; ++i) {
        const int k = 32 * s + ((lane >> 4) << 3) + i;
        const int col = 16 * n + (lane & 15);
        const float v = (col < D_OUT) ? pw4[k * D_OUT + col] : 0.f;
        const unsigned short h = f2bf(v);
        w4fh[(size_t)tid * 8 + i] = h;
        w4fl[(size_t)tid * 8 + i] = f2bf(v - bf2f(h));
    }
}

// ---------------------------------------------------------------------------
// Prep: pack W3 (64x128) into MFMA B-fragment order, split bf16 hi/lo.
// Fragment (s,n): s in {0,1} (k-step of 32), n in 0..7 (16-col tiles).
// ---------------------------------------------------------------------------
__global__ __launch_bounds__(256) void k_w3frag(const float* __restrict__ pw3,
                                                unsigned short* __restrict__ w3fh,
                                                unsigned short* __restrict__ w3fl) {
    const int tid = blockIdx.x * 256 + threadIdx.x;
    if (tid >= 2 * 8 * 64) return;
    const int lane = tid & 63;
    const int sn = tid >> 6;
    const int s = sn >> 3, n = sn & 7;
#pragma unroll
    for (int i = 0; i < 8; ++i) {
        const int k = 32 * s + ((lane >> 4) << 3) + i;
        const int col = 16 * n + (lane & 15);
        const float v = pw3[k * 128 + col];
        const unsigned short h = f2bf(v);
        w3fh[(size_t)tid * 8 + i] = h;
        w3fl[(size_t)tid * 8 + i] = f2bf(v - bf2f(h));
    }
}

// ---------------------------------------------------------------------------
// Fused point MLP + segmented max. Block = 2 keypoints, 320 threads (5 waves).
// Round-8 post-mortem: L4-MFMA left fp32 layer 3 (4096cy/wave-tile) + pw2/pw3
// s_load chains dominating. Now layer 3 is MFMA too:
//   1b (waves 0-3, lane=pair): gather + L1 (regs) + L2 quarter fp32 (pw2 from
//       LDS broadcasts) -> write x2 DIRECTLY as split-bf16 A-frags (a2h/a2l).
//   L3 (all 5 waves): MFMA M64xN128xK64, A=a2 (LDS b128), B=w3f (global,
//       coalesced); bias+relu on C-frags; u16-scatter into a3 frag layout.
//   L4 (all 5 waves): MFMA as round 8 + running segmented max.
// Pipeline: 1b(0); bar; { L3; bar; L4+max || 1b(next); bar } -- L4 (MFMA pipe)
// overlaps next 1b (VALU pipe). Stale tail rows masked at max-update.
// LDS = 8K (pw2L) + 16K (a2) + 32K (a3) = 56 KB -> 2 blocks/CU.
// ---------------------------------------------------------------------------
__global__ __launch_bounds__(320, 2) void fused_point(
    const float* __restrict__ features, const float* __restrict__ coords,
    const int* __restrict__ keypoints, const int* __restrict__ set_indices,
    const int* __restrict__ pairlist, const int* __restrict__ off,
    const float* __restrict__ pw1, const float* __restrict__ pb1,
    const float* __restrict__ pw2, const float* __restrict__ pb2,
    const float* __restrict__ pb3,
    const short8* __restrict__ w3fh, const short8* __restrict__ w3fl,
    const short8* __restrict__ w4fh, const short8* __restrict__ w4fl,
    const float* __restrict__ pb4,
    float* __restrict__ agg)
{
    __shared__ float  pw2L[32 * 64];  //  8 KB staged pw2
    __shared__ short8 a2h[512];       //  8 KB x2 hi A-frags: (s*4+m)*64+lane
    __shared__ short8 a2l[512];       //  8 KB
    __shared__ short8 a3h[1024];      // 16 KB x3 hi A-frags
    __shared__ short8 a3l[1024];      // 16 KB

    unsigned short* const a3hu = (unsigned short*)a3h;
    unsigned short* const a3lu = (unsigned short*)a3l;

    const int t    = threadIdx.x;
    const int gA   = blockIdx.x * 2;
    const int lane = t & 63;
    const int qq   = __builtin_amdgcn_readfirstlane(t >> 6); // wave id 0..4

    // stage pw2 (coalesced)
    for (int i = t; i < 32 * 64; i += 320) pw2L[i] = pw2[i];

    const int base   = off[gA];
    const int bnd    = off[gA + 1];
    const int endAll = off[gA + 2];
    const int nt     = (endAll - base + TP - 1) >> 6;

    // L3 n-tiles for this wave (hoisted bias loads)
    const int   n0 = qq;                 // always < 8
    const int   n1 = qq + 5;             // valid only if < 8
    const float b3_0 = pb3[16 * n0 + (lane & 15)];
    const float b3_1 = (n1 < 8) ? pb3[16 * n1 + (lane & 15)] : 0.f;

    float vA[4] = {-INFINITY, -INFINITY, -INFINITY, -INFINITY};
    float vB[4] = {-INFINITY, -INFINITY, -INFINITY, -INFINITY};

    // ---- 1b: gather + L1 + L2 quarter -> split-bf16 A-frags in a2 ----
    auto do_1b = [&](int it) {
        const int t0 = base + (it << 6);
        const int np = endAll - t0;
        if (qq < 4 && lane < np && lane < TP) {
            const int pair = pairlist[t0 + lane];
            const int pt = set_indices[pair];
            const int st = set_indices[N_PAIRS + pair];
            const int kp = keypoints[st];

            float x0[4];
            x0[0] = features[pt];
            x0[1] = coords[pt * 3 + 0] - coords[kp * 3 + 0];
            x0[2] = coords[pt * 3 + 1] - coords[kp * 3 + 1];
            x0[3] = coords[pt * 3 + 2] - coords[kp * 3 + 2];

            float x1[32];
#pragma unroll
            for (int j = 0; j < 32; ++j) {
                float a = pb1[j];
#pragma unroll
                for (int k = 0; k < 4; ++k) a = fmaf(x0[k], pw1[k * 32 + j], a);
                x1[j] = fmaxf(a, 0.f);
            }

            const int jc = qq << 4;            // 0,16,32,48 (wave-uniform)
            float acc[16];
#pragma unroll
            for (int jj = 0; jj < 16; ++jj) acc[jj] = pb2[jc + jj];
#pragma unroll
            for (int k = 0; k < 32; ++k) {
                const float xk = x1[k];
                const float4 w0 = *(const float4*)&pw2L[k * 64 + jc];
                const float4 w1 = *(const float4*)&pw2L[k * 64 + jc + 4];
                const float4 w2 = *(const float4*)&pw2L[k * 64 + jc + 8];
                const float4 w3 = *(const float4*)&pw2L[k * 64 + jc + 12];
                acc[0]  = fmaf(xk, w0.x, acc[0]);  acc[1]  = fmaf(xk, w0.y, acc[1]);
                acc[2]  = fmaf(xk, w0.z, acc[2]);  acc[3]  = fmaf(xk, w0.w, acc[3]);
                acc[4]  = fmaf(xk, w1.x, acc[4]);  acc[5]  = fmaf(xk, w1.y, acc[5]);
                acc[6]  = fmaf(xk, w1.z, acc[6]);  acc[7]  = fmaf(xk, w1.w, acc[7]);
                acc[8]  = fmaf(xk, w2.x, acc[8]);  acc[9]  = fmaf(xk, w2.y, acc[9]);
                acc[10] = fmaf(xk, w2.z, acc[10]); acc[11] = fmaf(xk, w2.w, acc[11]);
                acc[12] = fmaf(xk, w3.x, acc[12]); acc[13] = fmaf(xk, w3.y, acc[13]);
                acc[14] = fmaf(xk, w3.z, acc[14]); acc[15] = fmaf(xk, w3.w, acc[15]);
            }

            // x2 feats f = 16qq + jj: s = qq>>1; jj 0-7 -> q3 = (2qq)&3,
            // jj 8-15 -> q3+1. Slot = (s*4 + pair>>4)*64 + q3*16 + (pair&15).
            short8 vh0, vl0, vh1, vl1;
#pragma unroll
            for (int i = 0; i < 8; ++i) {
                const float v = fmaxf(acc[i], 0.f);
                const unsigned short h = f2bf(v);
                vh0[i] = (short)h; vl0[i] = (short)f2bf(v - bf2f(h));
                const float v2 = fmaxf(acc[8 + i], 0.f);
                const unsigned short h2 = f2bf(v2);
                vh1[i] = (short)h2; vl1[i] = (short)f2bf(v2 - bf2f(h2));
            }
            const int s2 = qq >> 1;
            const int fi = (s2 * 4 + (lane >> 4)) * 64 +
                           ((2 * qq) & 3) * 16 + (lane & 15);
            a2h[fi] = vh0;  a2l[fi] = vl0;
            a2h[fi + 16] = vh1;  a2l[fi + 16] = vl1;
        }
    };

    // ---- L3 C-frag -> a3 frag scatter (bias+relu+split-bf16) ----
    auto scatter3 = [&](const f32x4 (&c)[4], int n, float bias) {
        const int s4 = n >> 1;
        const int q3 = (2 * n + ((lane & 15) >> 3)) & 3;
        const int eb = (s4 * 256 + q3 * 16 + 4 * (lane >> 4)) * 8 + (lane & 7);
#pragma unroll
        for (int m = 0; m < 4; ++m) {
#pragma unroll
            for (int rr = 0; rr < 4; ++rr) {
                const float v = fmaxf(c[m][rr] + bias, 0.f);
                const unsigned short h = f2bf(v);
                const int e = eb + m * 512 + rr * 8;
                a3hu[e] = h;
                a3lu[e] = f2bf(v - bf2f(h));
            }
        }
    };

    __syncthreads();   // pw2L ready
    do_1b(0);
    __syncthreads();   // a2 ready

    for (int it = 0; it < nt; ++it) {
        // ---- L3: MFMA M64 x N128 x K64 (split-bf16, 3 terms) ----
        {
            f32x4 c0[4], c1[4];
#pragma unroll
            for (int m = 0; m < 4; ++m) {
                c0[m] = (f32x4){0.f, 0.f, 0.f, 0.f};
                c1[m] = (f32x4){0.f, 0.f, 0.f, 0.f};
            }
#pragma unroll
            for (int s = 0; s < 2; ++s) {
                short8 ah[4], al[4];
#pragma unroll
                for (int m = 0; m < 4; ++m) {
                    ah[m] = a2h[(s * 4 + m) * 64 + lane];
                    al[m] = a2l[(s * 4 + m) * 64 + lane];
                }
                {
                    const short8 bh = w3fh[(s * 8 + n0) * 64 + lane];
                    const short8 bl = w3fl[(s * 8 + n0) * 64 + lane];
#pragma unroll
                    for (int m = 0; m < 4; ++m) {
                        c0[m] = __builtin_amdgcn_mfma_f32_16x16x32_bf16(ah[m], bh, c0[m], 0, 0, 0);
                        c0[m] = __builtin_amdgcn_mfma_f32_16x16x32_bf16(al[m], bh, c0[m], 0, 0, 0);
                        c0[m] = __builtin_amdgcn_mfma_f32_16x16x32_bf16(ah[m], bl, c0[m], 0, 0, 0);
                    }
                }
                if (n1 < 8) {
                    const short8 bh = w3fh[(s * 8 + n1) * 64 + lane];
                    const short8 bl = w3fl[(s * 8 + n1) * 64 + lane];
#pragma unroll
                    for (int m = 0; m < 4; ++m) {
                        c1[m] = __builtin_amdgcn_mfma_f32_16x16x32_bf16(ah[m], bh, c1[m], 0, 0, 0);
                        c1[m] = __builtin_amdgcn_mfma_f32_16x16x32_bf16(al[m], bh, c1[m], 0, 0, 0);
                        c1[m] = __builtin_amdgcn_mfma_f32_16x16x32_bf16(ah[m], bl, c1[m], 0, 0, 0);
                    }
                }
            }
            scatter3(c0, n0, b3_0);
            if (n1 < 8) scatter3(c1, n1, b3_1);
        }
        __syncthreads();   // a3 ready; a2 free for next 1b

        // ---- L4: MFMA (as round 8) + running seg-max; overlap next 1b ----
        {
            const int t0 = base + (it << 6);
            f32x4 acc[4][4];
#pragma unroll
            for (int m = 0; m < 4; ++m)
#pragma unroll
                for (int j = 0; j < 4; ++j)
                    acc[m][j] = (f32x4){0.f, 0.f, 0.f, 0.f};

#pragma unroll
            for (int s = 0; s < 4; ++s) {
                short8 ah[4], al[4];
#pragma unroll
                for (int m = 0; m < 4; ++m) {
                    ah[m] = a3h[(s * 4 + m) * 64 + lane];
                    al[m] = a3l[(s * 4 + m) * 64 + lane];
                }
#pragma unroll
                for (int j = 0; j < 4; ++j) {
                    const int gn = qq + 5 * j;          // wave-uniform
                    if (gn < NTILES) {
                        const short8 bh = w4fh[(s * NTILES + gn) * 64 + lane];
                        const short8 bl = w4fl[(s * NTILES + gn) * 64 + lane];
#pragma unroll
                        for (int m = 0; m < 4; ++m) {
                            acc[m][j] = __builtin_amdgcn_mfma_f32_16x16x32_bf16(ah[m], bh, acc[m][j], 0, 0, 0);
                            acc[m][j] = __builtin_amdgcn_mfma_f32_16x16x32_bf16(al[m], bh, acc[m][j], 0, 0, 0);
                            acc[m][j] = __builtin_amdgcn_mfma_f32_16x16x32_bf16(ah[m], bl, acc[m][j], 0, 0, 0);
                        }
                    }
                }
            }

            // C/D: col = lane&15 (tile-local), row = (lane>>4)*4 + reg + 16m
            const int rb0 = (lane >> 4) << 2;
#pragma unroll
            for (int m = 0; m < 4; ++m) {
#pragma unroll
                for (int r = 0; r < 4; ++r) {
                    const int g = t0 + 16 * m + rb0 + r;
                    const bool vld = (g < endAll);
                    const bool inA = (g < bnd);
#pragma unroll
                    for (int j = 0; j < 4; ++j) {
                        const float c = acc[m][j][r];
                        vA[j] = (vld && inA)  ? fmaxf(vA[j], c) : vA[j];
                        vB[j] = (vld && !inA) ? fmaxf(vB[j], c) : vB[j];
                    }
                }
            }

            if (it + 1 < nt) do_1b(it + 1);   // writes a2 (L3 done with it)
        }
        __syncthreads();   // a3 free for next L3; a2 ready
    }

    // column reduce across row-groups; lanes 0-15 hold all cols
#pragma unroll
    for (int j = 0; j < 4; ++j) {
        vA[j] = fmaxf(vA[j], __shfl_xor(vA[j], 16));
        vA[j] = fmaxf(vA[j], __shfl_xor(vA[j], 32));
        vB[j] = fmaxf(vB[j], __shfl_xor(vB[j], 16));
        vB[j] = fmaxf(vB[j], __shfl_xor(vB[j], 32));
    }
    if (lane < 16) {
#pragma unroll
        for (int j = 0; j < 4; ++j) {
            const int gn = qq + 5 * j;
            const int col = 16 * gn + lane;
            if (gn < NTILES && col < D_OUT) {
                // empty segment: -inf + bias -> relu gives 0 (= max(segmax,0))
                agg[(size_t)gA * D_OUT + col]       = fmaxf(vA[j] + pb4[col], 0.f);
                agg[(size_t)(gA + 1) * D_OUT + col] = fmaxf(vB[j] + pb4[col], 0.f);
            }
        }
    }
}

// ---------------------------------------------------------------------------
// Output MLP. TR=16 (round-8 profile: TR=32's 76.8KB LDS -> 1 block/CU).
// In-place safe: block reads its 16 rows into LDS before writing them.
// ---------------------------------------------------------------------------
__global__ __launch_bounds__(320, 4) void out_mlp(
    const float* __restrict__ agg,
    const float* __restrict__ ow1, const float* __restrict__ ob1,
    const float* __restrict__ ow2, const float* __restrict__ ob2,
    float* __restrict__ y)
{
    __shared__ float A[TR * D_OUT];
    __shared__ float H[TR * D_OUT];
    const int t = threadIdx.x;
    const long rb = (long)blockIdx.x * TR;

    for (int l = t; l < TR * D_OUT; l += 320) A[l] = agg[rb * D_OUT + l];
    __syncthreads();

    if (t < D_OUT) {
        float acc[TR];
#pragma unroll
        for (int r = 0; r < TR; ++r) acc[r] = ob1[t];
        for (int k = 0; k < D_OUT; k += 4) {
            const float w0 = ow1[(k + 0) * D_OUT + t];
            const float w1 = ow1[(k + 1) * D_OUT + t];
            const float w2 = ow1[(k + 2) * D_OUT + t];
            const float w3 = ow1[(k + 3) * D_OUT + t];
#pragma unroll
            for (int r = 0; r < TR; ++r) {
                const float4 a4 = *reinterpret_cast<const float4*>(&A[r * D_OUT + k]);
                acc[r] = fmaf(a4.x, w0, acc[r]);
                acc[r] = fmaf(a4.y, w1, acc[r]);
                acc[r] = fmaf(a4.z, w2, acc[r]);
                acc[r] = fmaf(a4.w, w3, acc[r]);
            }
        }
#pragma unroll
        for (int r = 0; r < TR; ++r) H[r * D_OUT + t] = fmaxf(acc[r], 0.f);
    }
    __syncthreads();

    if (t < D_OUT) {
        float acc[TR];
#pragma unroll
        for (int r = 0; r < TR; ++r) acc[r] = ob2[t];
        for (int k = 0; k < D_OUT; k += 4) {
            const float w0 = ow2[(k + 0) * D_OUT + t];
            const float w1 = ow2[(k + 1) * D_OUT + t];
            const float w2 = ow2[(k + 2) * D_OUT + t];
            const float w3 = ow2[(k + 3) * D_OUT + t];
#pragma unroll
            for (int r = 0; r < TR; ++r) {
                const float4 h4 = *reinterpret_cast<const float4*>(&H[r * D_OUT + k]);
                acc[r] = fmaf(h4.x, w0, acc[r]);
                acc[r] = fmaf(h4.y, w1, acc[r]);
                acc[r] = fmaf(h4.z, w2, acc[r]);
                acc[r] = fmaf(h4.w, w3, acc[r]);
            }
        }
#pragma unroll
        for (int r = 0; r < TR; ++r) y[(rb + r) * D_OUT + t] = fmaxf(acc[r], 0.f);
    }
}

extern "C" void kernel_launch(void* const* d_in, const int* in_sizes, int n_in,
                              void* d_out, int out_size, void* d_ws, size_t ws_size,
                              hipStream_t stream) {
    const float* features    = (const float*)d_in[0];
    const float* coords      = (const float*)d_in[1];
    const int*   keypoints   = (const int*)d_in[2];
    const int*   set_indices = (const int*)d_in[3];
    const float* pw1 = (const float*)d_in[4];
    const float* pb1 = (const float*)d_in[5];
    const float* pw2 = (const float*)d_in[6];
    const float* pb2 = (const float*)d_in[7];
    const float* pw3 = (const float*)d_in[8];
    const float* pb3 = (const float*)d_in[9];
    const float* pw4 = (const float*)d_in[10];
    const float* pb4 = (const float*)d_in[11];
    const float* ow1 = (const float*)d_in[12];
    const float* ob1 = (const float*)d_in[13];
    const float* ow2 = (const float*)d_in[14];
    const float* ob2 = (const float*)d_in[15];

    const int* si_set = set_indices + N_PAIRS;

    // ws layout (~2.7 MB): cnt | off | cursor | w4f h/l | w3f h/l | pairlist
    char* w = (char*)d_ws;
    int*            cnt      = (int*)w;             w += 65536;
    int*            off      = (int*)w;             w += 65792;
    int*            cursor   = (int*)w;             w += 65536;
    unsigned short* w4fh     = (unsigned short*)w;  w += 4 * NTILES * 64 * 8 * 2;  // 77824
    unsigned short* w4fl     = (unsigned short*)w;  w += 4 * NTILES * 64 * 8 * 2;
    unsigned short* w3fh     = (unsigned short*)w;  w += 2 * 8 * 64 * 8 * 2;       // 16384
    unsigned short* w3fl     = (unsigned short*)w;  w += 2 * 8 * 64 * 8 * 2;
    int*            pairlist = (int*)w;

    float* agg = (float*)d_out;   // out_mlp runs in-place (read-before-write)
    float* y   = (float*)d_out;

    hipMemsetAsync(cnt, 0, 65536, stream);
    k_w4frag<<<(4 * NTILES * 64 + 255) / 256, 256, 0, stream>>>(pw4, w4fh, w4fl);
    k_w3frag<<<(2 * 8 * 64 + 255) / 256, 256, 0, stream>>>(pw3, w3fh, w3fl);
    k_count<<<N_PAIRS / 256, 256, 0, stream>>>(si_set, cnt);
    k_scan<<<1, 256, 0, stream>>>(cnt, off, cursor);
    k_fill<<<N_PAIRS / 256, 256, 0, stream>>>(si_set, cursor, pairlist);

    fused_point<<<N_KEYPOINTS / 2, 320, 0, stream>>>(
        features, coords, keypoints, set_indices, pairlist, off,
        pw1, pb1, pw2, pb2, pb3,
        (const short8*)w3fh, (const short8*)w3fl,
        (const short8*)w4fh, (const short8*)w4fl, pb4, agg);

    out_mlp<<<N_KEYPOINTS / TR, 320, 0, stream>>>(agg, ow1, ob1, ow2, ob2, y);
}

// Round 10
// 658.565 us; speedup vs baseline: 3.5630x; 1.3294x over previous
//
#include <hip/hip_runtime.h>

#define N_POINTS    100000
#define N_KEYPOINTS 16384
#define N_PAIRS     524288
#define D_OUT       300
#define NTILES      19     // ceil(304/16) column tiles for layer 4
#define ONT         19     // out-MLP n tiles (304)
#define OKS         10     // out-MLP k steps (300 -> 320)
#define TP          64     // pairs per LDS tile

typedef __attribute__((ext_vector_type(8))) short short8;   // 8 bf16 (4 VGPRs)
typedef __attribute__((ext_vector_type(4))) float f32x4;

__device__ inline unsigned short f2bf(float f) {           // RNE fp32 -> bf16
    unsigned u = __builtin_bit_cast(unsigned, f);
    u += 0x7FFFu + ((u >> 16) & 1u);
    return (unsigned short)(u >> 16);
}
__device__ inline float bf2f(unsigned short h) {
    unsigned u = ((unsigned)h) << 16;
    return __builtin_bit_cast(float, u);
}

// ---------------------------------------------------------------------------
// CSR build
// ---------------------------------------------------------------------------
__global__ __launch_bounds__(256) void k_count(const int* __restrict__ si_set,
                                               int* __restrict__ cnt) {
    const int s = blockIdx.x * 256 + threadIdx.x;
    if (s < N_PAIRS) atomicAdd(&cnt[si_set[s]], 1);
}

__global__ __launch_bounds__(256) void k_scan(const int* __restrict__ cnt,
                                              int* __restrict__ off,
                                              int* __restrict__ cursor) {
    __shared__ int part[256];
    const int t = threadIdx.x;
    const int base = t * 64;
    int s = 0;
    for (int k = 0; k < 64; ++k) s += cnt[base + k];
    part[t] = s;
    __syncthreads();
    for (int d = 1; d < 256; d <<= 1) {
        int add = (t >= d) ? part[t - d] : 0;
        __syncthreads();
        part[t] += add;
        __syncthreads();
    }
    int run = part[t] - s;
    for (int k = 0; k < 64; ++k) {
        off[base + k] = run;
        cursor[base + k] = run;
        run += cnt[base + k];
    }
    if (t == 255) off[N_KEYPOINTS] = run;
}

__global__ __launch_bounds__(256) void k_fill(const int* __restrict__ si_set,
                                              int* __restrict__ cursor,
                                              int* __restrict__ pairlist) {
    const int s = blockIdx.x * 256 + threadIdx.x;
    if (s < N_PAIRS) {
        const int st = si_set[s];
        const int pos = atomicAdd(&cursor[st], 1);
        pairlist[pos] = s;
    }
}

// ---------------------------------------------------------------------------
// Weight fragment packers (B-frag order: lane l -> col 16n+(l&15),
// k = 32s + (l>>4)*8 + i), split bf16 hi/lo.
// ---------------------------------------------------------------------------
__global__ __launch_bounds__(256) void k_w4frag(const float* __restrict__ pw4,
                                                unsigned short* __restrict__ fh,
                                                unsigned short* __restrict__ fl) {
    const int tid = blockIdx.x * 256 + threadIdx.x;
    if (tid >= 4 * NTILES * 64) return;
    const int lane = tid & 63;
    const int sn = tid >> 6;
    const int s = sn / NTILES, n = sn % NTILES;
#pragma unroll
    for (int i = 0; i < 8; ++i) {
        const int k = 32 * s + ((lane >> 4) << 3) + i;
        const int col = 16 * n + (lane & 15);
        const float v = (col < D_OUT) ? pw4[k * D_OUT + col] : 0.f;
        const unsigned short h = f2bf(v);
        fh[(size_t)tid * 8 + i] = h;
        fl[(size_t)tid * 8 + i] = f2bf(v - bf2f(h));
    }
}

__global__ __launch_bounds__(256) void k_w3frag(const float* __restrict__ pw3,
                                                unsigned short* __restrict__ fh,
                                                unsigned short* __restrict__ fl) {
    const int tid = blockIdx.x * 256 + threadIdx.x;
    if (tid >= 2 * 8 * 64) return;
    const int lane = tid & 63;
    const int sn = tid >> 6;
    const int s = sn >> 3, n = sn & 7;
#pragma unroll
    for (int i = 0; i < 8; ++i) {
        const int k = 32 * s + ((lane >> 4) << 3) + i;
        const int col = 16 * n + (lane & 15);
        const float v = pw3[k * 128 + col];
        const unsigned short h = f2bf(v);
        fh[(size_t)tid * 8 + i] = h;
        fl[(size_t)tid * 8 + i] = f2bf(v - bf2f(h));
    }
}

__global__ __launch_bounds__(256) void k_w2frag(const float* __restrict__ pw2,
                                                unsigned short* __restrict__ fh,
                                                unsigned short* __restrict__ fl) {
    const int tid = blockIdx.x * 256 + threadIdx.x;
    if (tid >= 4 * 64) return;     // s=0 only, 4 n-tiles
    const int lane = tid & 63;
    const int n = tid >> 6;
#pragma unroll
    for (int i = 0; i < 8; ++i) {
        const int k = ((lane >> 4) << 3) + i;
        const int col = 16 * n + (lane & 15);
        const float v = pw2[k * 64 + col];
        const unsigned short h = f2bf(v);
        fh[(size_t)tid * 8 + i] = h;
        fl[(size_t)tid * 8 + i] = f2bf(v - bf2f(h));
    }
}

// out-MLP weights: 300x300, K padded to 320, N padded to 304
__global__ __launch_bounds__(256) void k_owfrag(const float* __restrict__ src,
                                                unsigned short* __restrict__ fh,
                                                unsigned short* __restrict__ fl) {
    const int tid = blockIdx.x * 256 + threadIdx.x;
    if (tid >= OKS * ONT * 64) return;
    const int lane = tid & 63;
    const int sn = tid >> 6;
    const int s = sn / ONT, n = sn % ONT;
#pragma unroll
    for (int i = 0; i < 8; ++i) {
        const int k = 32 * s + ((lane >> 4) << 3) + i;
        const int col = 16 * n + (lane & 15);
        const float v = (k < D_OUT && col < D_OUT) ? src[k * D_OUT + col] : 0.f;
        const unsigned short h = f2bf(v);
        fh[(size_t)tid * 8 + i] = h;
        fl[(size_t)tid * 8 + i] = f2bf(v - bf2f(h));
    }
}

// ---------------------------------------------------------------------------
// Fused point MLP + segmented max. Block = 2 keypoints, 320 threads (5 waves).
// Round-9 post-mortem: 60% stall from gather chase latency, fp32-L2's 128
// ds_read_b128/thread, and tail-tile padding. Now:
//   phase A: gather(it+1) prefetch (T14) + L3-MFMA (a2 -> scatter a3)
//   phase B: L4-MFMA + seg-max  ||  L1 (32 FMA/lane, no redundancy) -> a1
//   phase C: L2-MFMA (a1 x w2f -> scatter a2)
// All MFMA/scatter m-loops guarded by npc (block-uniform) -> no padding work.
// LDS = 8K(a1) + 16K(a2) + 32K(a3) = 56 KB -> 2 blocks/CU.
// ---------------------------------------------------------------------------
__global__ __launch_bounds__(320, 2) void fused_point(
    const float* __restrict__ features, const float* __restrict__ coords,
    const int* __restrict__ keypoints, const int* __restrict__ set_indices,
    const int* __restrict__ pairlist, const int* __restrict__ off,
    const float* __restrict__ pw1, const float* __restrict__ pb1,
    const short8* __restrict__ w2fh, const short8* __restrict__ w2fl,
    const float* __restrict__ pb2,
    const short8* __restrict__ w3fh, const short8* __restrict__ w3fl,
    const float* __restrict__ pb3,
    const short8* __restrict__ w4fh, const short8* __restrict__ w4fl,
    const float* __restrict__ pb4,
    float* __restrict__ agg)
{
    __shared__ short8 a1h[256],  a1l[256];    //  8 KB x1 A-frags (K=32)
    __shared__ short8 a2h[512],  a2l[512];    // 16 KB x2 A-frags (K=64)
    __shared__ short8 a3h[1024], a3l[1024];   // 32 KB x3 A-frags (K=128)

    unsigned short* const a2hu = (unsigned short*)a2h;
    unsigned short* const a2lu = (unsigned short*)a2l;
    unsigned short* const a3hu = (unsigned short*)a3h;
    unsigned short* const a3lu = (unsigned short*)a3l;

    const int t    = threadIdx.x;
    const int gA   = blockIdx.x * 2;
    const int lane = t & 63;
    const int qq   = __builtin_amdgcn_readfirstlane(t >> 6); // 0..4

    const int base   = off[gA];
    const int bnd    = off[gA + 1];
    const int endAll = off[gA + 2];
    const int nt     = (endAll - base + TP - 1) >> 6;

    // L3 n-tile assignment + hoisted biases
    const int   n0 = qq;
    const int   n1 = qq + 5;
    const float b3_0 = pb3[16 * n0 + (lane & 15)];
    const float b3_1 = (n1 < 8) ? pb3[16 * n1 + (lane & 15)] : 0.f;
    const float b2   = (qq < 4) ? pb2[16 * qq + (lane & 15)] : 0.f;

    float vA[4] = {-INFINITY, -INFINITY, -INFINITY, -INFINITY};
    float vB[4] = {-INFINITY, -INFINITY, -INFINITY, -INFINITY};

    // prefetched gather state (for tile `git`)
    bool  pvalid = false;
    float x0n[4] = {0.f, 0.f, 0.f, 0.f};

    auto gather = [&](int git) {
        const int t0 = base + (git << 6);
        int np = endAll - t0; if (np > TP) np = TP;
        const int pr = 16 * qq + (lane & 15);
        pvalid = (qq < 4) && (pr < np);
        if (pvalid) {
            const int pair = pairlist[t0 + pr];
            const int pt = set_indices[pair];
            const int st = set_indices[N_PAIRS + pair];
            const int kp = keypoints[st];
            x0n[0] = features[pt];
            x0n[1] = coords[pt * 3 + 0] - coords[kp * 3 + 0];
            x0n[2] = coords[pt * 3 + 1] - coords[kp * 3 + 1];
            x0n[3] = coords[pt * 3 + 2] - coords[kp * 3 + 2];
        }
    };

    // L1 slice: wave qq, pair 16qq+(lane&15), cols 8*(lane>>4)..+8 -> a1 frag
    auto l1pack = [&]() {
        if (qq < 4) {
            const int jg = lane >> 4;
            short8 vh, vl;
            if (pvalid) {
#pragma unroll
                for (int i = 0; i < 8; ++i) {
                    const int j = 8 * jg + i;
                    float a = pb1[j];
#pragma unroll
                    for (int k = 0; k < 4; ++k)
                        a = fmaf(x0n[k], pw1[k * 32 + j], a);
                    a = fmaxf(a, 0.f);
                    const unsigned short h = f2bf(a);
                    vh[i] = (short)h;
                    vl[i] = (short)f2bf(a - bf2f(h));
                }
            } else {
#pragma unroll
                for (int i = 0; i < 8; ++i) { vh[i] = 0; vl[i] = 0; }
            }
            a1h[qq * 64 + lane] = vh;
            a1l[qq * 64 + lane] = vl;
        }
    };

    // L2-MFMA: M64 x N64 x K32; wave qq<4 does n-tile qq; scatter into a2.
    auto l2mfma = [&](int git) {
        const int t0 = base + (git << 6);
        int np = endAll - t0; if (np > TP) np = TP;
        if (qq < 4) {
            f32x4 c[4];
#pragma unroll
            for (int m = 0; m < 4; ++m) c[m] = (f32x4){0.f, 0.f, 0.f, 0.f};
            const short8 bh = w2fh[qq * 64 + lane];
            const short8 bl = w2fl[qq * 64 + lane];
#pragma unroll
            for (int m = 0; m < 4; ++m) {
                if (16 * m < np) {
                    const short8 ah = a1h[m * 64 + lane];
                    const short8 al = a1l[m * 64 + lane];
                    c[m] = __builtin_amdgcn_mfma_f32_16x16x32_bf16(ah, bh, c[m], 0, 0, 0);
                    c[m] = __builtin_amdgcn_mfma_f32_16x16x32_bf16(al, bh, c[m], 0, 0, 0);
                    c[m] = __builtin_amdgcn_mfma_f32_16x16x32_bf16(ah, bl, c[m], 0, 0, 0);
                }
            }
            // scatter: feat F = 16qq+(lane&15); s2=F>>5; kg=(F>>3)&3; i=lane&7
            const int s2 = qq >> 1;
            const int kg = (2 * qq + ((lane & 15) >> 3)) & 3;
            const int eb = (s2 * 256 + kg * 16 + 4 * (lane >> 4)) * 8 + (lane & 7);
#pragma unroll
            for (int m = 0; m < 4; ++m) {
                if (16 * m < np) {
#pragma unroll
                    for (int r = 0; r < 4; ++r) {
                        const float v = fmaxf(c[m][r] + b2, 0.f);
                        const unsigned short h = f2bf(v);
                        const int e = eb + m * 512 + r * 8;
                        a2hu[e] = h;
                        a2lu[e] = f2bf(v - bf2f(h));
                    }
                }
            }
        }
    };

    // L3 C-frag -> a3 scatter (proven round-9 formula + m guard)
    auto scatter3 = [&](const f32x4 (&c)[4], int n, float bias, int npc) {
        const int s4 = n >> 1;
        const int q3 = (2 * n + ((lane & 15) >> 3)) & 3;
        const int eb = (s4 * 256 + q3 * 16 + 4 * (lane >> 4)) * 8 + (lane & 7);
#pragma unroll
        for (int m = 0; m < 4; ++m) {
            if (16 * m < npc) {
#pragma unroll
                for (int rr = 0; rr < 4; ++rr) {
                    const float v = fmaxf(c[m][rr] + bias, 0.f);
                    const unsigned short h = f2bf(v);
                    const int e = eb + m * 512 + rr * 8;
                    a3hu[e] = h;
                    a3lu[e] = f2bf(v - bf2f(h));
                }
            }
        }
    };

    // prologue
    if (nt > 0) {
        gather(0);
        l1pack();
        __syncthreads();            // a1 ready
        l2mfma(0);
    }
    __syncthreads();                // a2 ready

    for (int it = 0; it < nt; ++it) {
        const int t0 = base + (it << 6);
        int npc = endAll - t0; if (npc > TP) npc = TP;
        const bool more = (it + 1) < nt;

        // ---------------- Phase A: gather prefetch + L3 ----------------
        if (more) gather(it + 1);
        {
            f32x4 c0[4], c1[4];
#pragma unroll
            for (int m = 0; m < 4; ++m) {
                c0[m] = (f32x4){0.f, 0.f, 0.f, 0.f};
                c1[m] = (f32x4){0.f, 0.f, 0.f, 0.f};
            }
#pragma unroll
            for (int s = 0; s < 2; ++s) {
                short8 ah[4], al[4];
#pragma unroll
                for (int m = 0; m < 4; ++m) {
                    ah[m] = a2h[(s * 4 + m) * 64 + lane];
                    al[m] = a2l[(s * 4 + m) * 64 + lane];
                }
                {
                    const short8 bh = w3fh[(s * 8 + n0) * 64 + lane];
                    const short8 bl = w3fl[(s * 8 + n0) * 64 + lane];
#pragma unroll
                    for (int m = 0; m < 4; ++m) {
                        if (16 * m < npc) {
                            c0[m] = __builtin_amdgcn_mfma_f32_16x16x32_bf16(ah[m], bh, c0[m], 0, 0, 0);
                            c0[m] = __builtin_amdgcn_mfma_f32_16x16x32_bf16(al[m], bh, c0[m], 0, 0, 0);
                            c0[m] = __builtin_amdgcn_mfma_f32_16x16x32_bf16(ah[m], bl, c0[m], 0, 0, 0);
                        }
                    }
                }
                if (n1 < 8) {
                    const short8 bh = w3fh[(s * 8 + n1) * 64 + lane];
                    const short8 bl = w3fl[(s * 8 + n1) * 64 + lane];
#pragma unroll
                    for (int m = 0; m < 4; ++m) {
                        if (16 * m < npc) {
                            c1[m] = __builtin_amdgcn_mfma_f32_16x16x32_bf16(ah[m], bh, c1[m], 0, 0, 0);
                            c1[m] = __builtin_amdgcn_mfma_f32_16x16x32_bf16(al[m], bh, c1[m], 0, 0, 0);
                            c1[m] = __builtin_amdgcn_mfma_f32_16x16x32_bf16(ah[m], bl, c1[m], 0, 0, 0);
                        }
                    }
                }
            }
            scatter3(c0, n0, b3_0, npc);
            if (n1 < 8) scatter3(c1, n1, b3_1, npc);
        }
        __syncthreads();            // a3 ready

        // ---------------- Phase B: L4 + seg-max  ||  L1(it+1) ----------------
        {
            f32x4 acc[4][4];
#pragma unroll
            for (int m = 0; m < 4; ++m)
#pragma unroll
                for (int j = 0; j < 4; ++j)
                    acc[m][j] = (f32x4){0.f, 0.f, 0.f, 0.f};

#pragma unroll
            for (int s = 0; s < 4; ++s) {
                short8 ah[4], al[4];
#pragma unroll
                for (int m = 0; m < 4; ++m) {
                    ah[m] = a3h[(s * 4 + m) * 64 + lane];
                    al[m] = a3l[(s * 4 + m) * 64 + lane];
                }
#pragma unroll
                for (int j = 0; j < 4; ++j) {
                    const int gn = qq + 5 * j;
                    if (gn < NTILES) {
                        const short8 bh = w4fh[(s * NTILES + gn) * 64 + lane];
                        const short8 bl = w4fl[(s * NTILES + gn) * 64 + lane];
#pragma unroll
                        for (int m = 0; m < 4; ++m) {
                            if (16 * m < npc) {
                                acc[m][j] = __builtin_amdgcn_mfma_f32_16x16x32_bf16(ah[m], bh, acc[m][j], 0, 0, 0);
                                acc[m][j] = __builtin_amdgcn_mfma_f32_16x16x32_bf16(al[m], bh, acc[m][j], 0, 0, 0);
                                acc[m][j] = __builtin_amdgcn_mfma_f32_16x16x32_bf16(ah[m], bl, acc[m][j], 0, 0, 0);
                            }
                        }
                    }
                }
            }

            const int rb0 = (lane >> 4) << 2;
#pragma unroll
            for (int m = 0; m < 4; ++m) {
#pragma unroll
                for (int r = 0; r < 4; ++r) {
                    const int g = t0 + 16 * m + rb0 + r;
                    const bool vld = (g < endAll);
                    const bool inA = (g < bnd);
#pragma unroll
                    for (int j = 0; j < 4; ++j) {
                        const float c = acc[m][j][r];
                        vA[j] = (vld && inA)  ? fmaxf(vA[j], c) : vA[j];
                        vB[j] = (vld && !inA) ? fmaxf(vB[j], c) : vB[j];
                    }
                }
            }

            if (more) l1pack();     // a1 free since last phase C
        }
        __syncthreads();            // a1 ready; a3 free

        // ---------------- Phase C: L2-MFMA(it+1) ----------------
        if (more) l2mfma(it + 1);
        __syncthreads();            // a2 ready
    }

    // column reduce across row-groups; lanes 0-15 hold all cols
#pragma unroll
    for (int j = 0; j < 4; ++j) {
        vA[j] = fmaxf(vA[j], __shfl_xor(vA[j], 16));
        vA[j] = fmaxf(vA[j], __shfl_xor(vA[j], 32));
        vB[j] = fmaxf(vB[j], __shfl_xor(vB[j], 16));
        vB[j] = fmaxf(vB[j], __shfl_xor(vB[j], 32));
    }
    if (lane < 16) {
#pragma unroll
        for (int j = 0; j < 4; ++j) {
            const int gn = qq + 5 * j;
            const int col = 16 * gn + lane;
            if (gn < NTILES && col < D_OUT) {
                agg[(size_t)gA * D_OUT + col]       = fmaxf(vA[j] + pb4[col], 0.f);
                agg[(size_t)(gA + 1) * D_OUT + col] = fmaxf(vB[j] + pb4[col], 0.f);
            }
        }
    }
}

// ---------------------------------------------------------------------------
// Output MLP via MFMA. Block = 32 rows, 320 threads. Layer-1 A-frags loaded
// straight from global agg (lane's 8 k's contiguous); h scattered to LDS in
// A-frag layout (proven formula); layer 2 from LDS; scattered y stores.
// In-place safe: block touches only its own 32 rows. LDS 40 KB -> 4 blk/CU.
// ---------------------------------------------------------------------------
__global__ __launch_bounds__(320, 2) void k_out(
    const float* __restrict__ agg,
    const short8* __restrict__ o1fh, const short8* __restrict__ o1fl,
    const float* __restrict__ ob1,
    const short8* __restrict__ o2fh, const short8* __restrict__ o2fl,
    const float* __restrict__ ob2,
    float* __restrict__ y)
{
    __shared__ short8 hAh[OKS * 2 * 64];   // 20 KB  slot (s*2+m)*64+lane
    __shared__ short8 hAl[OKS * 2 * 64];   // 20 KB
    unsigned short* const hhu = (unsigned short*)hAh;
    unsigned short* const hlu = (unsigned short*)hAl;

    const int t    = threadIdx.x;
    const int lane = t & 63;
    const int qq   = __builtin_amdgcn_readfirstlane(t >> 6); // 0..4
    const int rb   = blockIdx.x * 32;

    float b1[4], b2[4];
#pragma unroll
    for (int j = 0; j < 4; ++j) {
        const int gn = qq + 5 * j;
        const int col = 16 * gn + (lane & 15);
        b1[j] = (gn < ONT && col < D_OUT) ? ob1[col] : 0.f;
        b2[j] = (gn < ONT && col < D_OUT) ? ob2[col] : 0.f;
    }

    // ---- layer 1: A from global ----
    f32x4 acc[2][4];
#pragma unroll
    for (int m = 0; m < 2; ++m)
#pragma unroll
        for (int j = 0; j < 4; ++j)
            acc[m][j] = (f32x4){0.f, 0.f, 0.f, 0.f};

#pragma unroll
    for (int s = 0; s < OKS; ++s) {
        short8 ah[2], al[2];
#pragma unroll
        for (int m = 0; m < 2; ++m) {
            const int row = rb + (lane & 15) + 16 * m;
            const int kb = 32 * s + ((lane >> 4) << 3);
#pragma unroll
            for (int i = 0; i < 8; ++i) {
                const int k = kb + i;
                const float v = (k < D_OUT) ? agg[(size_t)row * D_OUT + k] : 0.f;
                const unsigned short h = f2bf(v);
                ah[m][i] = (short)h;
                al[m][i] = (short)f2bf(v - bf2f(h));
            }
        }
#pragma unroll
        for (int j = 0; j < 4; ++j) {
            const int gn = qq + 5 * j;
            if (gn < ONT) {
                const short8 bh = o1fh[(s * ONT + gn) * 64 + lane];
                const short8 bl = o1fl[(s * ONT + gn) * 64 + lane];
#pragma unroll
                for (int m = 0; m < 2; ++m) {
                    acc[m][j] = __builtin_amdgcn_mfma_f32_16x16x32_bf16(ah[m], bh, acc[m][j], 0, 0, 0);
                    acc[m][j] = __builtin_amdgcn_mfma_f32_16x16x32_bf16(al[m], bh, acc[m][j], 0, 0, 0);
                    acc[m][j] = __builtin_amdgcn_mfma_f32_16x16x32_bf16(ah[m], bl, acc[m][j], 0, 0, 0);
                }
            }
        }
    }

    // ---- scatter h into LDS A-frag layout (cols>=300 are zeroed weights) ----
#pragma unroll
    for (int j = 0; j < 4; ++j) {
        const int gn = qq + 5 * j;
        if (gn < ONT) {
            const int s2 = (16 * gn + (lane & 15)) >> 5;
            const int kg = ((16 * gn + (lane & 15)) >> 3) & 3;
            const int eb = ((s2 * 2) * 64 + kg * 16 + 4 * (lane >> 4)) * 8 + (lane & 7);
#pragma unroll
            for (int m = 0; m < 2; ++m) {
#pragma unroll
                for (int r = 0; r < 4; ++r) {
                    const float v = fmaxf(acc[m][j][r] + b1[j], 0.f);
                    const unsigned short h = f2bf(v);
                    const int e = eb + m * 512 + r * 8;
                    hhu[e] = h;
                    hlu[e] = f2bf(v - bf2f(h));
                }
            }
        }
    }
    __syncthreads();

    // ---- layer 2: A from LDS ----
    f32x4 acc2[2][4];
#pragma unroll
    for (int m = 0; m < 2; ++m)
#pragma unroll
        for (int j = 0; j < 4; ++j)
            acc2[m][j] = (f32x4){0.f, 0.f, 0.f, 0.f};

#pragma unroll
    for (int s = 0; s < OKS; ++s) {
        short8 ah[2], al[2];
#pragma unroll
        for (int m = 0; m < 2; ++m) {
            ah[m] = hAh[(s * 2 + m) * 64 + lane];
            al[m] = hAl[(s * 2 + m) * 64 + lane];
        }
#pragma unroll
        for (int j = 0; j < 4; ++j) {
            const int gn = qq + 5 * j;
            if (gn < ONT) {
                const short8 bh = o2fh[(s * ONT + gn) * 64 + lane];
                const short8 bl = o2fl[(s * ONT + gn) * 64 + lane];
#pragma unroll
                for (int m = 0; m < 2; ++m) {
                    acc2[m][j] = __builtin_amdgcn_mfma_f32_16x16x32_bf16(ah[m], bh, acc2[m][j], 0, 0, 0);
                    acc2[m][j] = __builtin_amdgcn_mfma_f32_16x16x32_bf16(al[m], bh, acc2[m][j], 0, 0, 0);
                    acc2[m][j] = __builtin_amdgcn_mfma_f32_16x16x32_bf16(ah[m], bl, acc2[m][j], 0, 0, 0);
                }
            }
        }
    }

    // ---- store y ----
    const int rb0 = (lane >> 4) << 2;
#pragma unroll
    for (int m = 0; m < 2; ++m) {
#pragma unroll
        for (int r = 0; r < 4; ++r) {
            const int row = rb + rb0 + r + 16 * m;
#pragma unroll
            for (int j = 0; j < 4; ++j) {
                const int gn = qq + 5 * j;
                const int col = 16 * gn + (lane & 15);
                if (gn < ONT && col < D_OUT)
                    y[(size_t)row * D_OUT + col] = fmaxf(acc2[m][j][r] + b2[j], 0.f);
            }
        }
    }
}

extern "C" void kernel_launch(void* const* d_in, const int* in_sizes, int n_in,
                              void* d_out, int out_size, void* d_ws, size_t ws_size,
                              hipStream_t stream) {
    const float* features    = (const float*)d_in[0];
    const float* coords      = (const float*)d_in[1];
    const int*   keypoints   = (const int*)d_in[2];
    const int*   set_indices = (const int*)d_in[3];
    const float* pw1 = (const float*)d_in[4];
    const float* pb1 = (const float*)d_in[5];
    const float* pw2 = (const float*)d_in[6];
    const float* pb2 = (const float*)d_in[7];
    const float* pw3 = (const float*)d_in[8];
    const float* pb3 = (const float*)d_in[9];
    const float* pw4 = (const float*)d_in[10];
    const float* pb4 = (const float*)d_in[11];
    const float* ow1 = (const float*)d_in[12];
    const float* ob1 = (const float*)d_in[13];
    const float* ow2 = (const float*)d_in[14];
    const float* ob2 = (const float*)d_in[15];

    const int* si_set = set_indices + N_PAIRS;

    // ws layout (~3.3 MB)
    char* w = (char*)d_ws;
    int*            cnt      = (int*)w;             w += 65536;
    int*            off      = (int*)w;             w += 65792;
    int*            cursor   = (int*)w;             w += 65536;
    unsigned short* w4fh     = (unsigned short*)w;  w += 4 * NTILES * 64 * 8 * 2;  // 77824
    unsigned short* w4fl     = (unsigned short*)w;  w += 4 * NTILES * 64 * 8 * 2;
    unsigned short* w3fh     = (unsigned short*)w;  w += 2 * 8 * 64 * 8 * 2;       // 16384
    unsigned short* w3fl     = (unsigned short*)w;  w += 2 * 8 * 64 * 8 * 2;
    unsigned short* w2fh     = (unsigned short*)w;  w += 4 * 64 * 8 * 2;           // 4096
    unsigned short* w2fl     = (unsigned short*)w;  w += 4 * 64 * 8 * 2;
    unsigned short* o1fh     = (unsigned short*)w;  w += OKS * ONT * 64 * 8 * 2;   // 194560
    unsigned short* o1fl     = (unsigned short*)w;  w += OKS * ONT * 64 * 8 * 2;
    unsigned short* o2fh     = (unsigned short*)w;  w += OKS * ONT * 64 * 8 * 2;
    unsigned short* o2fl     = (unsigned short*)w;  w += OKS * ONT * 64 * 8 * 2;
    int*            pairlist = (int*)w;

    float* agg = (float*)d_out;   // k_out runs in-place (per-block row disjoint)
    float* y   = (float*)d_out;

    hipMemsetAsync(cnt, 0, 65536, stream);
    k_w4frag<<<(4 * NTILES * 64 + 255) / 256, 256, 0, stream>>>(pw4, w4fh, w4fl);
    k_w3frag<<<(2 * 8 * 64 + 255) / 256, 256, 0, stream>>>(pw3, w3fh, w3fl);
    k_w2frag<<<1, 256, 0, stream>>>(pw2, w2fh, w2fl);
    k_owfrag<<<(OKS * ONT * 64 + 255) / 256, 256, 0, stream>>>(ow1, o1fh, o1fl);
    k_owfrag<<<(OKS * ONT * 64 + 255) / 256, 256, 0, stream>>>(ow2, o2fh, o2fl);
    k_count<<<N_PAIRS / 256, 256, 0, stream>>>(si_set, cnt);
    k_scan<<<1, 256, 0, stream>>>(cnt, off, cursor);
    k_fill<<<N_PAIRS / 256, 256, 0, stream>>>(si_set, cursor, pairlist);

    fused_point<<<N_KEYPOINTS / 2, 320, 0, stream>>>(
        features, coords, keypoints, set_indices, pairlist, off,
        pw1, pb1,
        (const short8*)w2fh, (const short8*)w2fl, pb2,
        (const short8*)w3fh, (const short8*)w3fl, pb3,
        (const short8*)w4fh, (const short8*)w4fl, pb4, agg);

    k_out<<<N_KEYPOINTS / 32, 320, 0, stream>>>(
        agg,
        (const short8*)o1fh, (const short8*)o1fl, ob1,
        (const short8*)o2fh, (const short8*)o2fl, ob2, y);
}